// Round 6
// baseline (519.029 us; speedup 1.0000x reference)
//
#include <hip/hip_runtime.h>
#include <hip/hip_bf16.h>
#include <math.h>

#define T_   2048
#define C_   2048
#define H_   16
#define N_   128
#define KVH_ 4

typedef __bf16 bf16x8 __attribute__((ext_vector_type(8)));
typedef __bf16 bf16x4 __attribute__((ext_vector_type(4)));
typedef float  f32x4  __attribute__((ext_vector_type(4)));

#define MFMA16(a, b, c) __builtin_amdgcn_mfma_f32_16x16x32_bf16(a, b, c, 0, 0, 0)

// async global->LDS, 16B per lane; LDS dest = wave-uniform base + lane*16
static __device__ __forceinline__ void gll16(const __bf16* g, __bf16* l) {
    __builtin_amdgcn_global_load_lds((const __attribute__((address_space(1))) void*)g,
                                     (__attribute__((address_space(3))) void*)l, 16, 0, 0);
}

static __device__ __forceinline__ float wave_sum_shfl(float v) {
#pragma unroll
    for (int m = 32; m >= 1; m >>= 1) v += __shfl_xor(v, m, 64);
    return v;
}
static __device__ __forceinline__ float block_sum_128(float v, float* sh2) {
    v = wave_sum_shfl(v);
    if ((threadIdx.x & 63) == 0) sh2[threadIdx.x >> 6] = v;
    __syncthreads();
    float r = sh2[0] + sh2[1];
    __syncthreads();
    return r;
}

// ---------------- xm = bf16(x * mask) ----------------
__global__ void xm_to_bf16(const float* __restrict__ x, const float* __restrict__ mask,
                           __bf16* __restrict__ o) {
    int idx = blockIdx.x * 256 + threadIdx.x;
    int e = idx * 4;
    float4 v = *(const float4*)(x + e);
    float m = mask[e >> 11];
    bf16x4 r;
    r.x = (__bf16)(v.x * m); r.y = (__bf16)(v.y * m);
    r.z = (__bf16)(v.z * m); r.w = (__bf16)(v.w * m);
    *(bf16x4*)(o + e) = r;
}

// ---------------- batched tiled transpose f32 (R x C) -> bf16 (C x R) ----------------
struct TrDesc { const float* src; __bf16* dst; int R, C, tileStart; };
struct TrBatch { TrDesc d[13]; int n; };

__global__ void transpose_batch(TrBatch tb) {
    int bid = blockIdx.x;
    int e = 0;
    while (e + 1 < tb.n && tb.d[e + 1].tileStart <= bid) e++;
    const float* src = tb.d[e].src;
    __bf16* dst = tb.d[e].dst;
    int R = tb.d[e].R, C = tb.d[e].C;
    int tix = bid - tb.d[e].tileStart;
    int tilesC = (C + 31) >> 5;
    int trow = tix / tilesC, tcol = tix - trow * tilesC;
    int r0 = trow * 32, c0 = tcol * 32;
    __shared__ float tile[32][33];
    int tx = threadIdx.x & 31, ty = threadIdx.x >> 5;
#pragma unroll
    for (int i = 0; i < 4; i++) {
        int r = r0 + ty + i * 8, c = c0 + tx;
        if (r < R && c < C) tile[ty + i * 8][tx] = src[(size_t)r * C + c];
    }
    __syncthreads();
#pragma unroll
    for (int i = 0; i < 4; i++) {
        int c = c0 + ty + i * 8, r = r0 + tx;
        if (c < C && r < R) dst[(size_t)c * R + r] = (__bf16)tile[tx][ty + i * 8];
    }
}

__global__ void transpose_f32_bf16(const float* __restrict__ src, __bf16* __restrict__ dst,
                                   int R, int C) {
    __shared__ float tile[32][33];
    int tx = threadIdx.x & 31, ty = threadIdx.x >> 5;
    int c0 = blockIdx.x * 32, r0 = blockIdx.y * 32;
#pragma unroll
    for (int i = 0; i < 4; i++) {
        int r = r0 + ty + i * 8, c = c0 + tx;
        if (r < R && c < C) tile[ty + i * 8][tx] = src[(size_t)r * C + c];
    }
    __syncthreads();
#pragma unroll
    for (int i = 0; i < 4; i++) {
        int c = c0 + ty + i * 8, r = r0 + tx;
        if (c < C && r < R) dst[(size_t)c * R + r] = (__bf16)tile[tx][ty + i * 8];
    }
}

// ---------------- MFMA GEMM: C[M,N] = A[M,K] @ BT[N,K]^T ----------------
template <int MODE>
__global__ __launch_bounds__(256, 2)
void gemm_bf16(const __bf16* __restrict__ A, int lda, const __bf16* __restrict__ BT,
               const float* __restrict__ bias, float* __restrict__ Cf,
               __bf16* __restrict__ Cb, int N, int K, int act) {
    __shared__ __align__(16) __bf16 As[128 * 32];
    __shared__ __align__(16) __bf16 Bs[128 * 32];
    const int tid = threadIdx.x;
    const int lane = tid & 63, wave = tid >> 6;
    const int bm = blockIdx.y * 128, bn = blockIdx.x * 128;
    const int wm = (wave >> 1) * 64, wn = (wave & 1) * 64;
    const int prow = lane >> 2, pk = (lane & 3) * 8;
    const __bf16* ApA = A + (size_t)(bm + wave * 32 + prow) * lda + pk;
    const __bf16* BpA = BT + (size_t)(bn + wave * 32 + prow) * K + pk;
    const bool bokA = (bn + wave * 32 + prow) < N;
    const bool bokB = (bn + wave * 32 + 16 + prow) < N;
    __bf16* AsD = As + wave * 1024;
    __bf16* BsD = Bs + wave * 1024;
    const int lm = lane & 15, lq = lane >> 4;
    f32x4 acc[4][4] = {};
    for (int k0 = 0; k0 < K; k0 += 32) {
        __syncthreads();
        gll16(ApA + k0, AsD);
        gll16(ApA + (size_t)16 * lda + k0, AsD + 512);
        if (bokA) gll16(BpA + k0, BsD);
        if (bokB) gll16(BpA + (size_t)16 * K + k0, BsD + 512);
        __syncthreads();
        bf16x8 af[4], bfr[4];
#pragma unroll
        for (int i = 0; i < 4; i++)
            af[i] = *(const bf16x8*)(As + (wm + i * 16 + lm) * 32 + lq * 8);
#pragma unroll
        for (int j = 0; j < 4; j++)
            bfr[j] = *(const bf16x8*)(Bs + (wn + j * 16 + lm) * 32 + lq * 8);
#pragma unroll
        for (int i = 0; i < 4; i++)
#pragma unroll
            for (int j = 0; j < 4; j++)
                acc[i][j] = MFMA16(af[i], bfr[j], acc[i][j]);
    }
#pragma unroll
    for (int j = 0; j < 4; j++) {
        int col = bn + wn + j * 16 + lm;
        if (col >= N) continue;
        float bv = (MODE == 0 && bias) ? bias[col] : 0.f;
#pragma unroll
        for (int i = 0; i < 4; i++) {
            int row0 = bm + wm + i * 16 + lq * 4;
#pragma unroll
            for (int rg = 0; rg < 4; rg++) {
                float v = acc[i][j][rg] + bv;
                int row = row0 + rg;
                if (MODE == 0) {
                    if (act == 1) v = tanhf(v);
                    else if (act == 2) v = 1.f / (1.f + __expf(-v));
                    Cf[(size_t)row * N + col] = v;
                } else {
                    if (col < 3072) {
                        Cf[(size_t)row * 3072 + col] = v;
                    } else {
                        float vv = v;
                        if (col < 3232) vv = tanhf(v);
                        else if (col >= 3456) vv = 1.f / (1.f + __expf(-v));
                        Cb[(size_t)row * 544 + (col - 3072)] = (__bf16)vv;
                    }
                }
            }
        }
    }
}

// ---------------- grouped down-projection GEMM (one launch, 5 segments) ----
struct GSeg { const __bf16* BT; const float* bias; float* Cf; int aoff, K, N, act, bx0; };
struct GB5 { GSeg s[5]; };

__global__ __launch_bounds__(256, 2)
void gemm_group(const __bf16* __restrict__ Abase, GB5 gb) {
    __shared__ __align__(16) __bf16 As[128 * 32];
    __shared__ __align__(16) __bf16 Bs[128 * 32];
    int e = 0;
    while (e + 1 < 5 && gb.s[e + 1].bx0 <= (int)blockIdx.x) e++;
    const GSeg sg = gb.s[e];
    const int K = sg.K, N = sg.N;
    const __bf16* A = Abase + sg.aoff;
    const int tid = threadIdx.x;
    const int lane = tid & 63, wave = tid >> 6;
    const int bm = blockIdx.y * 128, bn = (blockIdx.x - sg.bx0) * 128;
    const int wm = (wave >> 1) * 64, wn = (wave & 1) * 64;
    const int prow = lane >> 2, pk = (lane & 3) * 8;
    const __bf16* ApA = A + (size_t)(bm + wave * 32 + prow) * 544 + pk;
    const __bf16* BpA = sg.BT + (size_t)(bn + wave * 32 + prow) * K + pk;
    __bf16* AsD = As + wave * 1024;
    __bf16* BsD = Bs + wave * 1024;
    const int lm = lane & 15, lq = lane >> 4;
    f32x4 acc[4][4] = {};
    for (int k0 = 0; k0 < K; k0 += 32) {
        __syncthreads();
        gll16(ApA + k0, AsD);
        gll16(ApA + (size_t)16 * 544 + k0, AsD + 512);
        gll16(BpA + k0, BsD);
        gll16(BpA + (size_t)16 * K + k0, BsD + 512);
        __syncthreads();
        bf16x8 af[4], bfr[4];
#pragma unroll
        for (int i = 0; i < 4; i++)
            af[i] = *(const bf16x8*)(As + (wm + i * 16 + lm) * 32 + lq * 8);
#pragma unroll
        for (int j = 0; j < 4; j++)
            bfr[j] = *(const bf16x8*)(Bs + (wn + j * 16 + lm) * 32 + lq * 8);
#pragma unroll
        for (int i = 0; i < 4; i++)
#pragma unroll
            for (int j = 0; j < 4; j++)
                acc[i][j] = MFMA16(af[i], bfr[j], acc[i][j]);
    }
#pragma unroll
    for (int j = 0; j < 4; j++) {
        int col = bn + wn + j * 16 + lm;
        float bv = sg.bias ? sg.bias[col] : 0.f;
#pragma unroll
        for (int i = 0; i < 4; i++) {
            int row0 = bm + wm + i * 16 + lq * 4;
#pragma unroll
            for (int rg = 0; rg < 4; rg++) {
                float v = acc[i][j][rg] + bv;
                if (sg.act == 2) v = 1.f / (1.f + __expf(-v));
                sg.Cf[(size_t)(row0 + rg) * N + col] = v;
            }
        }
    }
}

// ---------------- prep for k/v (per (t,kvh)); mega row stride 3072 ----------------
__global__ __launch_bounds__(128)
void prep_kv(float* __restrict__ mega, float* __restrict__ kkO,
             const float* __restrict__ kfirst, const float* __restrict__ vfirst,
             const float* __restrict__ kmix, const float* __restrict__ vmix,
             const float* __restrict__ cosT, const float* __restrict__ sinT,
             const float* __restrict__ knw) {
    __shared__ float sh[128];
    __shared__ float sh2[2];
    int b = blockIdx.x;
    int t = b >> 2, kvh = b & 3;
    int n = threadIdx.x;
    size_t kbase = (size_t)t * 3072 + 2048 + kvh * 128;
    size_t vbase = (size_t)t * 3072 + 2560 + kvh * 128;
    size_t fbase = (size_t)t * 512 + kvh * 128;
    float x = mega[kbase + n];
    float ssq = block_sum_128(x * x, sh2);
    float kn = knw[n] * (x * rsqrtf(ssq * (1.f / 128.f) + 1e-6f));
    sh[n] = kn;
    __syncthreads();
    float rot = (n < 64) ? -sh[n + 64] : sh[n - 64];
    float c = cosT[(size_t)t * 128 + n], s = sinT[(size_t)t * 128 + n];
    float kr = kn * c + rot * s;
    float kf = kr + (kfirst[fbase + n] - kr) * kmix[fbase + n];
    float s2 = block_sum_128(kf * kf, sh2);
    float kkv = kf / fmaxf(sqrtf(s2), 1e-12f);
    float vv = mega[vbase + n];
    float vf = vv + (vfirst[fbase + n] - vv) * vmix[fbase + n];
    mega[kbase + n] = kf;
    kkO[fbase + n] = kkv;
    mega[vbase + n] = vf;
}

// ---------------- prep for r / wdec / c (per (t,h)) ----------------
__global__ __launch_bounds__(128)
void prep_r(float* __restrict__ mega, float* __restrict__ Wl,
            const float* __restrict__ rk, float* __restrict__ cOut,
            const float* __restrict__ cosT, const float* __restrict__ sinT,
            const float* __restrict__ rnw) {
    __shared__ float sh[128];
    __shared__ float sh2[2];
    int b = blockIdx.x;
    int t = b >> 4, h = b & 15;
    int kv = h >> 2;
    int n = threadIdx.x;
    size_t rbase = (size_t)t * 3072 + h * 128;
    float x = mega[rbase + n];
    float ssq = block_sum_128(x * x, sh2);
    float rn = rnw[n] * (x * rsqrtf(ssq * (1.f / 128.f) + 1e-6f));
    sh[n] = rn;
    __syncthreads();
    float rot = (n < 64) ? -sh[n + 64] : sh[n - 64];
    float c = cosT[(size_t)t * 128 + n], s = sinT[(size_t)t * 128 + n];
    float rr = rn * c + rot * s;
    mega[rbase + n] = rr;
    size_t wb_ = (size_t)t * 2048 + h * 128 + n;
    float z = Wl[wb_];
    float nz = -z;
    float sp = fmaxf(nz, 0.f) + log1pf(expf(-fabsf(nz)));
    float w = -sp - 0.5f;
    Wl[wb_] = expf(-expf(w));
    float pc = rr * mega[(size_t)t * 3072 + 2048 + kv * 128 + n] * rk[h * 128 + n];
    float cs = block_sum_128(pc, sh2);
    if (n == 0) cOut[b] = cs;
}

// =====================================================================
// Chunked scan, L=32, 64 chunks (WY/UT transform).
// Single-wave blocks, NO __syncthreads anywhere inside (wave-local LDS,
// per-wave DS ops are in-order) — avoids the compiler's vmcnt(0) drain
// before s_barrier, so global prefetch loads stay in flight.
// =====================================================================

// ---- phase A: per (head, chunk) = 1024 blocks x 1 wave -------------
__global__ __launch_bounds__(64)
void scan_phaseA(const float* __restrict__ Wl, const float* __restrict__ megaF,
                 const float* __restrict__ aS, const float* __restrict__ kkB,
                 __bf16* __restrict__ ATt_g, __bf16* __restrict__ Rr_g,
                 __bf16* __restrict__ Bnt_g, __bf16* __restrict__ Knt_g,
                 __bf16* __restrict__ Vt_g, __bf16* __restrict__ Gbt_g,
                 __bf16* __restrict__ Gkt_g, float* __restrict__ Cloc_g,
                 float* __restrict__ cwL_g) {
    __shared__ __align__(16) __bf16 pool[27648];
    __bf16* Arm = pool;            // [32][136]
    __bf16* Brm = pool + 4352;     // [32][136]
    __bf16* Krm = pool + 8704;     // [32][136]
    __bf16* Rrm = pool + 13056;    // [32][136]
    __bf16* Vt  = pool + 17408;    // [128][40]
    __bf16* Mrm = pool + 22528;    // [32][40]
    __bf16* Mt  = pool + 23808;    // [32][40]
    __bf16* Prm = pool + 25088;    // [32][40]
    __bf16* Gtmp= pool + 26368;    // [32][40]
    __bf16* M2rm = pool + 4352;
    __bf16* M2t  = pool + 5632;
    __bf16* Xa   = pool + 6912;
    __bf16* Xb   = pool + 8192;
    __bf16* Tt   = pool + 9472;    // [t'][s] = T[s][t']   stride 40
    __bf16* PTt  = pool + 10752;   // [t'][s] = (P*T)[s][t']
    __bf16* Ant  = pool + 13056;   // [n][s] stride 32 (overlays Rrm after copy-out)

    const int l = threadIdx.x, lm = l & 15, lq = l >> 4;
    const int u = blockIdx.x, h = u >> 6, c = u & 63, kv = h >> 2;
    const int n0 = l, n1 = l + 64;

    float cw0 = 1.f, cw1 = 1.f;
    for (int t = 0; t < 32; ++t) {
        int tg = c * 32 + t;
        size_t hb = (size_t)tg * 2048 + h * 128;
        size_t mb = (size_t)tg * 3072;
        size_t kb = (size_t)tg * 512 + kv * 128;
        float wv0 = Wl[hb + n0], wv1 = Wl[hb + n1];
        float r0 = megaF[mb + h * 128 + n0], r1 = megaF[mb + h * 128 + n1];
        float q0 = kkB[kb + n0], q1 = kkB[kb + n1];
        float s0 = aS[hb + n0], s1 = aS[hb + n1];
        float k0 = megaF[mb + 2048 + kv * 128 + n0], k1 = megaF[mb + 2048 + kv * 128 + n1];
        float v0 = megaF[mb + 2560 + kv * 128 + n0], v1 = megaF[mb + 2560 + kv * 128 + n1];
        float cp0 = cw0, cp1 = cw1;
        cw0 *= wv0; cw1 *= wv1;
        float ic0 = 1.f / cw0, ic1 = 1.f / cw1;
        Arm[t * 136 + n0] = (__bf16)(-cp0 * q0);
        Arm[t * 136 + n1] = (__bf16)(-cp1 * q1);
        Brm[t * 136 + n0] = (__bf16)(q0 * s0 * ic0);
        Brm[t * 136 + n1] = (__bf16)(q1 * s1 * ic1);
        Krm[t * 136 + n0] = (__bf16)(k0 * ic0);
        Krm[t * 136 + n1] = (__bf16)(k1 * ic1);
        Rrm[t * 136 + n0] = (__bf16)(cw0 * r0);
        Rrm[t * 136 + n1] = (__bf16)(cw1 * r1);
        Vt[n0 * 40 + t] = (__bf16)v0;
        Vt[n1 * 40 + t] = (__bf16)v1;
    }
    cwL_g[(size_t)u * 128 + n0] = cw0;
    cwL_g[(size_t)u * 128 + n1] = cw1;

    auto mmLL = [&](const __bf16* Ao, const __bf16* Bo, bool incl, __bf16* dTr, __bf16* dDir) {
#pragma unroll
        for (int ri = 0; ri < 2; ri++)
#pragma unroll
        for (int ci = 0; ci < 2; ci++) {
            f32x4 acc = {};
#pragma unroll
            for (int s = 0; s < 4; s++) {
                bf16x8 af = *(const bf16x8*)(Ao + (ri * 16 + lm) * 136 + s * 32 + lq * 8);
                bf16x8 bf = *(const bf16x8*)(Bo + (ci * 16 + lm) * 136 + s * 32 + lq * 8);
                acc = MFMA16(af, bf, acc);
            }
#pragma unroll
            for (int rg = 0; rg < 4; rg++) {
                int rr = ri * 16 + lq * 4 + rg, cc = ci * 16 + lm;
                bool keep = incl ? (cc <= rr) : (cc < rr);
                __bf16 bv = (__bf16)(keep ? acc[rg] : 0.f);
                if (dTr)  dTr[cc * 40 + rr] = bv;
                if (dDir) dDir[rr * 40 + cc] = bv;
            }
        }
    };
    mmLL(Arm, Brm, false, Mrm, Mt);
    mmLL(Arm, Krm, false, Prm, nullptr);
    mmLL(Rrm, Brm, true, nullptr, Gtmp);
    for (int i = l; i < 512; i += 64) {
        int r = i >> 4, cp = i & 15;
        ((int*)(Gbt_g + (size_t)u * 1024))[i] = *(const int*)(Gtmp + r * 40 + cp * 2);
    }
    mmLL(Rrm, Krm, true, nullptr, Gtmp);
    for (int i = l; i < 512; i += 64) {
        int r = i >> 4, cp = i & 15;
        ((int*)(Gkt_g + (size_t)u * 1024))[i] = *(const int*)(Gtmp + r * 40 + cp * 2);
    }
    for (int i = l; i < 2048; i += 64) {
        int t = i >> 6, cp = i & 63;
        ((int*)(Rr_g + (size_t)u * 4096))[i] = *(const int*)(Rrm + t * 136 + cp * 2);
    }
    for (int i = l; i < 2048; i += 64) {
        int n = i >> 4, tp = i & 15;
        unsigned int lo = ((const unsigned short*)Brm)[(2 * tp) * 136 + n];
        unsigned int hi = ((const unsigned short*)Brm)[(2 * tp + 1) * 136 + n];
        ((unsigned int*)(Bnt_g + (size_t)u * 4096))[i] = lo | (hi << 16);
        unsigned int lo2 = ((const unsigned short*)Krm)[(2 * tp) * 136 + n];
        unsigned int hi2 = ((const unsigned short*)Krm)[(2 * tp + 1) * 136 + n];
        ((unsigned int*)(Knt_g + (size_t)u * 4096))[i] = lo2 | (hi2 << 16);
    }
    for (int i = l; i < 2048; i += 64) {
        int n = i >> 4, tp = i & 15;
        ((int*)(Vt_g + (size_t)u * 4096))[i] = *(const int*)(Vt + n * 40 + tp * 2);
    }

    // Xa = I + M ; Ant = A~^T (into Rrm region — reads above precede in order)
    for (int i = l; i < 1024; i += 64) {
        int s = i >> 5, t = i & 31;
        Xa[s * 40 + t] = (s == t) ? (__bf16)1.f : Mrm[s * 40 + t];
    }
    for (int i = l; i < 4096; i += 64) {
        int s = i & 31, n = i >> 5;
        Ant[n * 32 + s] = Arm[s * 136 + n];
    }

    auto mat32 = [&](const __bf16* Ao, const __bf16* Bo, const __bf16* accIn,
                     __bf16* oRm, __bf16* oT) {
#pragma unroll
        for (int ri = 0; ri < 2; ri++)
#pragma unroll
        for (int ci = 0; ci < 2; ci++) {
            f32x4 acc = {};
            if (accIn) {
#pragma unroll
                for (int rg = 0; rg < 4; rg++)
                    acc[rg] = (float)accIn[(ri * 16 + lq * 4 + rg) * 40 + ci * 16 + lm];
            }
            bf16x8 af = *(const bf16x8*)(Ao + (ri * 16 + lm) * 40 + lq * 8);
            bf16x8 bf = *(const bf16x8*)(Bo + (ci * 16 + lm) * 40 + lq * 8);
            acc = MFMA16(af, bf, acc);
#pragma unroll
            for (int rg = 0; rg < 4; rg++) {
                int rr = ri * 16 + lq * 4 + rg, cc = ci * 16 + lm;
                __bf16 bv = (__bf16)acc[rg];
                if (oRm) oRm[rr * 40 + cc] = bv;
                if (oT)  oT[cc * 40 + rr] = bv;
            }
        }
    };
    mat32(Mrm, Mt, nullptr, M2rm, M2t);
    mat32(Xa, M2t, Xa, Xb, nullptr);
    mat32(M2rm, M2t, nullptr, Mrm, Mt);
    mat32(Xb, Mt, Xb, Xa, nullptr);
    mat32(Mrm, Mt, nullptr, M2rm, M2t);
    mat32(Xa, M2t, Xa, Xb, nullptr);
    mat32(M2rm, M2t, nullptr, Mrm, Mt);
    mat32(Xb, Mt, Xb, nullptr, Tt);
    mat32(Tt, Prm, nullptr, PTt, nullptr);

    // ATt[t'][n] = sum_s T[s][t'] * A~[s][n] via MFMA
#pragma unroll
    for (int ti = 0; ti < 2; ti++) {
        bf16x8 af = *(const bf16x8*)(Tt + (ti * 16 + lm) * 40 + lq * 8);
#pragma unroll
        for (int ni = 0; ni < 8; ni++) {
            f32x4 accv = {};
            bf16x8 bfv = *(const bf16x8*)(Ant + (ni * 16 + lm) * 32 + lq * 8);
            accv = MFMA16(af, bfv, accv);
#pragma unroll
            for (int rg = 0; rg < 4; rg++)
                ATt_g[(size_t)u * 4096 + (ti * 16 + lq * 4 + rg) * 128 + ni * 16 + lm] = (__bf16)accv[rg];
        }
    }
    // C_loc = V * (P T)
#pragma unroll
    for (int ii = 0; ii < 8; ii++)
#pragma unroll
    for (int ti = 0; ti < 2; ti++) {
        f32x4 acc = {};
        bf16x8 af = *(const bf16x8*)(Vt + (ii * 16 + lm) * 40 + lq * 8);
        bf16x8 bf = *(const bf16x8*)(PTt + (ti * 16 + lm) * 40 + lq * 8);
        acc = MFMA16(af, bf, acc);
#pragma unroll
        for (int rg = 0; rg < 4; rg++)
            Cloc_g[(size_t)u * 4096 + (ii * 16 + lq * 4 + rg) * 32 + ti * 16 + lm] = acc[rg];
    }
}

// ---- phase B v3: 1 wave/block, barrier-free; 16 rows x 128 cols state ----
struct Ops {
    bf16x8 at[8], bn[8], kn[8], vf;
    f32x4 cl[2];
    float cw[8];
};

__global__ __launch_bounds__(64, 1)
void scan_phaseB(const __bf16* __restrict__ ATt_g, const __bf16* __restrict__ Bnt_g,
                 const __bf16* __restrict__ Knt_g, const __bf16* __restrict__ Vt_g,
                 const float* __restrict__ Cloc_g, const float* __restrict__ cwL_g,
                 __bf16* __restrict__ Sg, __bf16* __restrict__ Cg) {
    __shared__ __align__(16) __bf16 Sbf[16 * 136];
    __shared__ __align__(16) __bf16 Cbf[16 * 40];
    const int h = blockIdx.y, i0 = blockIdx.x * 16;
    const int l = threadIdx.x, lm = l & 15, lq = l >> 4;
    f32x4 st[8];
#pragma unroll
    for (int cc = 0; cc < 8; cc++) st[cc] = (f32x4){0.f, 0.f, 0.f, 0.f};

    auto loadOps = [&](int c, Ops& o) {
        size_t u = (size_t)h * 64 + c;
        const __bf16* ATp = ATt_g + u * 4096;
        const __bf16* Bp  = Bnt_g + u * 4096;
        const __bf16* Kp  = Knt_g + u * 4096;
#pragma unroll
        for (int ti = 0; ti < 2; ti++)
#pragma unroll
            for (int s = 0; s < 4; s++)
                o.at[ti * 4 + s] = *(const bf16x8*)(ATp + (ti * 16 + lm) * 128 + s * 32 + lq * 8);
#pragma unroll
        for (int cc = 0; cc < 8; cc++) {
            o.bn[cc] = *(const bf16x8*)(Bp + (cc * 16 + lm) * 32 + lq * 8);
            o.kn[cc] = *(const bf16x8*)(Kp + (cc * 16 + lm) * 32 + lq * 8);
        }
        o.vf = *(const bf16x8*)(Vt_g + u * 4096 + (size_t)(i0 + lm) * 32 + lq * 8);
#pragma unroll
        for (int ti = 0; ti < 2; ti++)
#pragma unroll
            for (int rg = 0; rg < 4; rg++)
                o.cl[ti][rg] = Cloc_g[u * 4096 + (i0 + lq * 4 + rg) * 32 + ti * 16 + lm];
#pragma unroll
        for (int cc = 0; cc < 8; cc++) o.cw[cc] = cwL_g[u * 128 + cc * 16 + lm];
    };

    auto computeChunk = [&](int c, const Ops& o) {
        size_t u = (size_t)h * 64 + c;
        // state (f32 C-layout) -> bf16 LDS [i][n]; wave-local, in-order DS
#pragma unroll
        for (int cc = 0; cc < 8; cc++)
#pragma unroll
            for (int rg = 0; rg < 4; rg++)
                Sbf[(lq * 4 + rg) * 136 + cc * 16 + lm] = (__bf16)st[cc][rg];
        bf16x8 saf[4];
#pragma unroll
        for (int s = 0; s < 4; s++)
            saf[s] = *(const bf16x8*)(Sbf + lm * 136 + s * 32 + lq * 8);
        f32x4 cacc[2];
#pragma unroll
        for (int ti = 0; ti < 2; ti++) {
            f32x4 acc = o.cl[ti];
#pragma unroll
            for (int s = 0; s < 4; s++) acc = MFMA16(saf[s], o.at[ti * 4 + s], acc);
            cacc[ti] = acc;
        }
#pragma unroll
        for (int ti = 0; ti < 2; ti++)
#pragma unroll
            for (int rg = 0; rg < 4; rg++)
                Cbf[(lq * 4 + rg) * 40 + ti * 16 + lm] = (__bf16)cacc[ti][rg];
        bf16x8 cf = *(const bf16x8*)(Cbf + lm * 40 + lq * 8);
        // dump S0 (A-frag layout) and C for phaseC — off the dependency chain
#pragma unroll
        for (int s = 0; s < 4; s++)
            *(bf16x8*)(Sg + u * 16384 + (size_t)(i0 + lm) * 128 + s * 32 + lq * 8) = saf[s];
        *(bf16x8*)(Cg + u * 4096 + (size_t)(i0 + lm) * 32 + lq * 8) = cf;
        // S = (S0 + C*B^T + V*K^T) * cwL
#pragma unroll
        for (int cc = 0; cc < 8; cc++) {
            st[cc] = MFMA16(cf, o.bn[cc], st[cc]);
            st[cc] = MFMA16(o.vf, o.kn[cc], st[cc]);
#pragma unroll
            for (int rg = 0; rg < 4; rg++) st[cc][rg] *= o.cw[cc];
        }
    };

    Ops A, B;
    loadOps(0, A);
    loadOps(1, B);
    for (int c = 0; c < 64; c += 2) {
        computeChunk(c, A);
        if (c + 2 < 64) loadOps(c + 2, A);
        computeChunk(c + 1, B);
        if (c + 3 < 64) loadOps(c + 3, B);
    }
}

// ---- phase C: Y = S0*R^ + C*Gb + V*Gk, fused output gating (1 wave, no barrier) ----
__global__ __launch_bounds__(64)
void scan_phaseC(const __bf16* __restrict__ Sg, const __bf16* __restrict__ Cg,
                 const __bf16* __restrict__ Rr_g, const __bf16* __restrict__ Vt_g,
                 const __bf16* __restrict__ Gbt_g, const __bf16* __restrict__ Gkt_g,
                 const float* __restrict__ cB, const float* __restrict__ megaF,
                 const float* __restrict__ gB, __bf16* __restrict__ out) {
    __shared__ float Ybuf[32 * 18];
    const int bx = blockIdx.x, h = blockIdx.y;
    const int c = bx >> 3, i0 = (bx & 7) * 16;
    const int l = threadIdx.x, lm = l & 15, lq = l >> 4;
    const size_t u = (size_t)h * 64 + c;
    bf16x8 saf[4];
#pragma unroll
    for (int s = 0; s < 4; s++)
        saf[s] = *(const bf16x8*)(Sg + u * 16384 + (size_t)(i0 + lm) * 128 + s * 32 + lq * 8);
    bf16x8 cf = *(const bf16x8*)(Cg + u * 4096 + (size_t)(i0 + lm) * 32 + lq * 8);
    bf16x8 vf = *(const bf16x8*)(Vt_g + u * 4096 + (size_t)(i0 + lm) * 32 + lq * 8);
#pragma unroll
    for (int ti = 0; ti < 2; ti++) {
        f32x4 acc = {};
#pragma unroll
        for (int s = 0; s < 4; s++) {
            bf16x8 rp = *(const bf16x8*)(Rr_g + u * 4096 + (ti * 16 + lm) * 128 + s * 32 + lq * 8);
            acc = MFMA16(saf[s], rp, acc);
        }
        bf16x8 gb = *(const bf16x8*)(Gbt_g + u * 1024 + (ti * 16 + lm) * 32 + lq * 8);
        acc = MFMA16(cf, gb, acc);
        bf16x8 gk = *(const bf16x8*)(Gkt_g + u * 1024 + (ti * 16 + lm) * 32 + lq * 8);
        acc = MFMA16(vf, gk, acc);
#pragma unroll
        for (int rg = 0; rg < 4; rg++)
            Ybuf[(ti * 16 + lm) * 18 + lq * 4 + rg] = acc[rg];
    }
    const int kv = h >> 2;
#pragma unroll
    for (int pass = 0; pass < 8; pass++) {
        int t = pass * 4 + lq;
        int tg = c * 32 + t;
        int col = h * 128 + i0 + lm;
        float yv = Ybuf[t * 18 + lm];
        float cv = cB[tg * 16 + h];
        float vv = megaF[(size_t)tg * 3072 + 2560 + kv * 128 + i0 + lm];
        float gg = gB[(size_t)tg * 2048 + col];
        out[(size_t)tg * 2048 + col] = (__bf16)((yv + cv * vv) * gg);
    }
}

// ---------------- orchestration ----------------
extern "C" void kernel_launch(void* const* d_in, const int* in_sizes, int n_in,
                              void* d_out, int out_size, void* d_ws, size_t ws_size,
                              hipStream_t stream) {
    (void)in_sizes; (void)n_in; (void)out_size; (void)ws_size;
    const float* x      = (const float*)d_in[0];
    const float* vfirst = (const float*)d_in[1];
    const float* kfirst = (const float*)d_in[2];
    const float* amask  = (const float*)d_in[3];
    const float* cosT   = (const float*)d_in[4];
    const float* sinT   = (const float*)d_in[5];
    const float* w0     = (const float*)d_in[6];
    const float* w1     = (const float*)d_in[7];
    const float* w2     = (const float*)d_in[8];
    const float* a0     = (const float*)d_in[9];
    const float* a1     = (const float*)d_in[10];
    const float* a2     = (const float*)d_in[11];
    const float* v0     = (const float*)d_in[12];
    const float* v1     = (const float*)d_in[13];
    const float* v2     = (const float*)d_in[14];
    const float* k0     = (const float*)d_in[15];
    const float* k1     = (const float*)d_in[16];
    const float* k2     = (const float*)d_in[17];
    const float* g1     = (const float*)d_in[18];
    const float* g2     = (const float*)d_in[19];
    const float* rk     = (const float*)d_in[20];
    const float* rnw    = (const float*)d_in[21];
    const float* knw    = (const float*)d_in[22];
    const float* W_r    = (const float*)d_in[23];
    const float* W_k    = (const float*)d_in[24];
    const float* W_v    = (const float*)d_in[25];
    const float* W_o    = (const float*)d_in[26];

    char* p = (char*)d_ws;
    auto take = [&](size_t bytes) { char* r = p; p += (bytes + 255) & ~(size_t)255; return r; };
    __bf16* arena   = (__bf16*)take((size_t)3616 * 2048 * 2);
    __bf16* xmb     = (__bf16*)take((size_t)T_ * C_ * 2);
    float*  megaF   = (float*)take((size_t)T_ * 3072 * 4);
    __bf16* megaB   = (__bf16*)take((size_t)T_ * 544 * 2);
    __bf16* w2T     = (__bf16*)take((size_t)2048 * 160 * 2);
    __bf16* a2T     = (__bf16*)take((size_t)2048 * 96 * 2);
    __bf16* v2T     = (__bf16*)take((size_t)512 * 64 * 2);
    __bf16* k2T     = (__bf16*)take((size_t)512 * 64 * 2);
    __bf16* g2T     = (__bf16*)take((size_t)2048 * 160 * 2);
    float*  Wl      = (float*)take((size_t)T_ * 2048 * 4);   // wdec; reused as Sg
    float*  aS      = (float*)take((size_t)T_ * 2048 * 4);   // a; tail of Sg
    float*  gB      = (float*)take((size_t)T_ * 2048 * 4);
    float*  kkB     = (float*)take((size_t)T_ * 512 * 4);    // kk; reused as Cg
    float*  vmx     = (float*)take((size_t)T_ * 512 * 4);    // tail of Cg
    float*  kmx     = (float*)take((size_t)T_ * 512 * 4);
    float*  cB      = (float*)take((size_t)T_ * H_ * 4);
    __bf16* ATt_g   = (__bf16*)take((size_t)1024 * 4096 * 2);
    __bf16* Rr_g    = (__bf16*)take((size_t)1024 * 4096 * 2);
    __bf16* Bnt_g   = (__bf16*)take((size_t)1024 * 4096 * 2);
    __bf16* Knt_g   = (__bf16*)take((size_t)1024 * 4096 * 2);
    __bf16* Vt_g    = (__bf16*)take((size_t)1024 * 4096 * 2);
    __bf16* Gbt_g   = (__bf16*)take((size_t)1024 * 1024 * 2);
    __bf16* Gkt_g   = (__bf16*)take((size_t)1024 * 1024 * 2);
    float*  Cloc_g  = (float*)take((size_t)1024 * 4096 * 4);
    float*  cwL_g   = (float*)take((size_t)1024 * 128 * 4);
    __bf16* Sg = (__bf16*)Wl;
    __bf16* Cg = (__bf16*)kkB;

    xm_to_bf16<<<(T_ * C_ / 4) / 256, 256, 0, stream>>>(x, amask, xmb);

    TrBatch tb;
    {
        const float* srcs[13] = {W_r, W_k, W_v, w1, a1, v1, k1, g1, w2, a2, v2, k2, g2};
        __bf16* dsts[13] = {arena, arena + (size_t)2048 * 2048, arena + (size_t)2560 * 2048,
                            arena + (size_t)3072 * 2048, arena + (size_t)3232 * 2048,
                            arena + (size_t)3328 * 2048, arena + (size_t)3392 * 2048,
                            arena + (size_t)3456 * 2048, w2T, a2T, v2T, k2T, g2T};
        int Rs[13] = {2048, 2048, 2048, 2048, 2048, 2048, 2048, 2048, 160, 96, 64, 64, 160};
        int Cs[13] = {2048, 512, 512, 160, 96, 64, 64, 160, 2048, 2048, 512, 512, 2048};
        int cum = 0;
        for (int e = 0; e < 13; e++) {
            tb.d[e].src = srcs[e]; tb.d[e].dst = dsts[e];
            tb.d[e].R = Rs[e]; tb.d[e].C = Cs[e]; tb.d[e].tileStart = cum;
            cum += ((Rs[e] + 31) / 32) * ((Cs[e] + 31) / 32);
        }
        tb.n = 13;
        transpose_batch<<<cum, 256, 0, stream>>>(tb);
    }

    gemm_bf16<2><<<dim3(29, 16), 256, 0, stream>>>(xmb, 2048, arena, nullptr, megaF, megaB, 3616, 2048, 0);

    GB5 gb;
    gb.s[0] = {w2T, w0, Wl,  0,   160, 2048, 0, 0};
    gb.s[1] = {a2T, a0, aS,  160, 96,  2048, 2, 16};
    gb.s[2] = {v2T, v0, vmx, 256, 64,  512,  2, 32};
    gb.s[3] = {k2T, k0, kmx, 320, 64,  512,  2, 36};
    gb.s[4] = {g2T, nullptr, gB, 384, 160, 2048, 0, 40};
    gemm_group<<<dim3(56, 16), 256, 0, stream>>>(megaB, gb);

    prep_kv<<<T_ * KVH_, 128, 0, stream>>>(megaF, kkB, kfirst, vfirst, kmx, vmx, cosT, sinT, knw);
    prep_r<<<T_ * H_, 128, 0, stream>>>(megaF, Wl, rk, cB, cosT, sinT, rnw);

    scan_phaseA<<<1024, 64, 0, stream>>>(Wl, megaF, aS, kkB, ATt_g, Rr_g, Bnt_g, Knt_g,
                                         Vt_g, Gbt_g, Gkt_g, Cloc_g, cwL_g);
    scan_phaseB<<<dim3(8, 16), 64, 0, stream>>>(ATt_g, Bnt_g, Knt_g, Vt_g, Cloc_g, cwL_g, Sg, Cg);
    scan_phaseC<<<dim3(512, 16), 64, 0, stream>>>(Sg, Cg, Rr_g, Vt_g, Gbt_g, Gkt_g,
                                                  cB, megaF, gB, xmb);

    transpose_f32_bf16<<<dim3(64, 64), 256, 0, stream>>>(W_o, arena, 2048, 2048);
    gemm_bf16<0><<<dim3(16, 16), 256, 0, stream>>>(xmb, 2048, arena, nullptr, (float*)d_out, nullptr, 2048, 2048, 0);
}

// Round 7
// 496.402 us; speedup vs baseline: 1.0456x; 1.0456x over previous
//
#include <hip/hip_runtime.h>
#include <hip/hip_bf16.h>
#include <math.h>

#define T_   2048
#define C_   2048
#define H_   16
#define N_   128
#define KVH_ 4

typedef __bf16 bf16x8 __attribute__((ext_vector_type(8)));
typedef __bf16 bf16x4 __attribute__((ext_vector_type(4)));
typedef float  f32x4  __attribute__((ext_vector_type(4)));

#define MFMA16(a, b, c) __builtin_amdgcn_mfma_f32_16x16x32_bf16(a, b, c, 0, 0, 0)

// async global->LDS, 16B per lane; LDS dest = wave-uniform base + lane*16
static __device__ __forceinline__ void gll16(const __bf16* g, __bf16* l) {
    __builtin_amdgcn_global_load_lds((const __attribute__((address_space(1))) void*)g,
                                     (__attribute__((address_space(3))) void*)l, 16, 0, 0);
}

static __device__ __forceinline__ float wave_sum_shfl(float v) {
#pragma unroll
    for (int m = 32; m >= 1; m >>= 1) v += __shfl_xor(v, m, 64);
    return v;
}
static __device__ __forceinline__ float block_sum_128(float v, float* sh2) {
    v = wave_sum_shfl(v);
    if ((threadIdx.x & 63) == 0) sh2[threadIdx.x >> 6] = v;
    __syncthreads();
    float r = sh2[0] + sh2[1];
    __syncthreads();
    return r;
}

// ---------------- xm = bf16(x * mask) ----------------
__global__ void xm_to_bf16(const float* __restrict__ x, const float* __restrict__ mask,
                           __bf16* __restrict__ o) {
    int idx = blockIdx.x * 256 + threadIdx.x;
    int e = idx * 4;
    float4 v = *(const float4*)(x + e);
    float m = mask[e >> 11];
    bf16x4 r;
    r.x = (__bf16)(v.x * m); r.y = (__bf16)(v.y * m);
    r.z = (__bf16)(v.z * m); r.w = (__bf16)(v.w * m);
    *(bf16x4*)(o + e) = r;
}

// ---------------- batched tiled transpose f32 (R x C) -> bf16 (C x R) ----------------
struct TrDesc { const float* src; __bf16* dst; int R, C, tileStart; };
struct TrBatch { TrDesc d[13]; int n; };

__global__ void transpose_batch(TrBatch tb) {
    int bid = blockIdx.x;
    int e = 0;
    while (e + 1 < tb.n && tb.d[e + 1].tileStart <= bid) e++;
    const float* src = tb.d[e].src;
    __bf16* dst = tb.d[e].dst;
    int R = tb.d[e].R, C = tb.d[e].C;
    int tix = bid - tb.d[e].tileStart;
    int tilesC = (C + 31) >> 5;
    int trow = tix / tilesC, tcol = tix - trow * tilesC;
    int r0 = trow * 32, c0 = tcol * 32;
    __shared__ float tile[32][33];
    int tx = threadIdx.x & 31, ty = threadIdx.x >> 5;
#pragma unroll
    for (int i = 0; i < 4; i++) {
        int r = r0 + ty + i * 8, c = c0 + tx;
        if (r < R && c < C) tile[ty + i * 8][tx] = src[(size_t)r * C + c];
    }
    __syncthreads();
#pragma unroll
    for (int i = 0; i < 4; i++) {
        int c = c0 + ty + i * 8, r = r0 + tx;
        if (c < C && r < R) dst[(size_t)c * R + r] = (__bf16)tile[tx][ty + i * 8];
    }
}

__global__ void transpose_f32_bf16(const float* __restrict__ src, __bf16* __restrict__ dst,
                                   int R, int C) {
    __shared__ float tile[32][33];
    int tx = threadIdx.x & 31, ty = threadIdx.x >> 5;
    int c0 = blockIdx.x * 32, r0 = blockIdx.y * 32;
#pragma unroll
    for (int i = 0; i < 4; i++) {
        int r = r0 + ty + i * 8, c = c0 + tx;
        if (r < R && c < C) tile[ty + i * 8][tx] = src[(size_t)r * C + c];
    }
    __syncthreads();
#pragma unroll
    for (int i = 0; i < 4; i++) {
        int c = c0 + ty + i * 8, r = r0 + tx;
        if (c < C && r < R) dst[(size_t)c * R + r] = (__bf16)tile[tx][ty + i * 8];
    }
}

// ---------------- MFMA GEMM: C[M,N] = A[M,K] @ BT[N,K]^T ----------------
template <int MODE>
__global__ __launch_bounds__(256, 2)
void gemm_bf16(const __bf16* __restrict__ A, int lda, const __bf16* __restrict__ BT,
               const float* __restrict__ bias, float* __restrict__ Cf,
               __bf16* __restrict__ Cb, int N, int K, int act) {
    __shared__ __align__(16) __bf16 As[128 * 32];
    __shared__ __align__(16) __bf16 Bs[128 * 32];
    const int tid = threadIdx.x;
    const int lane = tid & 63, wave = tid >> 6;
    const int bm = blockIdx.y * 128, bn = blockIdx.x * 128;
    const int wm = (wave >> 1) * 64, wn = (wave & 1) * 64;
    const int prow = lane >> 2, pk = (lane & 3) * 8;
    const __bf16* ApA = A + (size_t)(bm + wave * 32 + prow) * lda + pk;
    const __bf16* BpA = BT + (size_t)(bn + wave * 32 + prow) * K + pk;
    const bool bokA = (bn + wave * 32 + prow) < N;
    const bool bokB = (bn + wave * 32 + 16 + prow) < N;
    __bf16* AsD = As + wave * 1024;
    __bf16* BsD = Bs + wave * 1024;
    const int lm = lane & 15, lq = lane >> 4;
    f32x4 acc[4][4] = {};
    for (int k0 = 0; k0 < K; k0 += 32) {
        __syncthreads();
        gll16(ApA + k0, AsD);
        gll16(ApA + (size_t)16 * lda + k0, AsD + 512);
        if (bokA) gll16(BpA + k0, BsD);
        if (bokB) gll16(BpA + (size_t)16 * K + k0, BsD + 512);
        __syncthreads();
        bf16x8 af[4], bfr[4];
#pragma unroll
        for (int i = 0; i < 4; i++)
            af[i] = *(const bf16x8*)(As + (wm + i * 16 + lm) * 32 + lq * 8);
#pragma unroll
        for (int j = 0; j < 4; j++)
            bfr[j] = *(const bf16x8*)(Bs + (wn + j * 16 + lm) * 32 + lq * 8);
#pragma unroll
        for (int i = 0; i < 4; i++)
#pragma unroll
            for (int j = 0; j < 4; j++)
                acc[i][j] = MFMA16(af[i], bfr[j], acc[i][j]);
    }
#pragma unroll
    for (int j = 0; j < 4; j++) {
        int col = bn + wn + j * 16 + lm;
        if (col >= N) continue;
        float bv = (MODE == 0 && bias) ? bias[col] : 0.f;
#pragma unroll
        for (int i = 0; i < 4; i++) {
            int row0 = bm + wm + i * 16 + lq * 4;
#pragma unroll
            for (int rg = 0; rg < 4; rg++) {
                float v = acc[i][j][rg] + bv;
                int row = row0 + rg;
                if (MODE == 0) {
                    if (act == 1) v = tanhf(v);
                    else if (act == 2) v = 1.f / (1.f + __expf(-v));
                    Cf[(size_t)row * N + col] = v;
                } else {
                    if (col < 3072) {
                        Cf[(size_t)row * 3072 + col] = v;
                    } else {
                        float vv = v;
                        if (col < 3232) vv = tanhf(v);
                        else if (col >= 3456) vv = 1.f / (1.f + __expf(-v));
                        Cb[(size_t)row * 544 + (col - 3072)] = (__bf16)vv;
                    }
                }
            }
        }
    }
}

// ---------------- grouped down-projection GEMM (one launch, 5 segments) ----
struct GSeg { const __bf16* BT; const float* bias; float* Cf; int aoff, K, N, act, bx0; };
struct GB5 { GSeg s[5]; };

__global__ __launch_bounds__(256, 2)
void gemm_group(const __bf16* __restrict__ Abase, GB5 gb) {
    __shared__ __align__(16) __bf16 As[128 * 32];
    __shared__ __align__(16) __bf16 Bs[128 * 32];
    int e = 0;
    while (e + 1 < 5 && gb.s[e + 1].bx0 <= (int)blockIdx.x) e++;
    const GSeg sg = gb.s[e];
    const int K = sg.K, N = sg.N;
    const __bf16* A = Abase + sg.aoff;
    const int tid = threadIdx.x;
    const int lane = tid & 63, wave = tid >> 6;
    const int bm = blockIdx.y * 128, bn = (blockIdx.x - sg.bx0) * 128;
    const int wm = (wave >> 1) * 64, wn = (wave & 1) * 64;
    const int prow = lane >> 2, pk = (lane & 3) * 8;
    const __bf16* ApA = A + (size_t)(bm + wave * 32 + prow) * 544 + pk;
    const __bf16* BpA = sg.BT + (size_t)(bn + wave * 32 + prow) * K + pk;
    __bf16* AsD = As + wave * 1024;
    __bf16* BsD = Bs + wave * 1024;
    const int lm = lane & 15, lq = lane >> 4;
    f32x4 acc[4][4] = {};
    for (int k0 = 0; k0 < K; k0 += 32) {
        __syncthreads();
        gll16(ApA + k0, AsD);
        gll16(ApA + (size_t)16 * 544 + k0, AsD + 512);
        gll16(BpA + k0, BsD);
        gll16(BpA + (size_t)16 * K + k0, BsD + 512);
        __syncthreads();
        bf16x8 af[4], bfr[4];
#pragma unroll
        for (int i = 0; i < 4; i++)
            af[i] = *(const bf16x8*)(As + (wm + i * 16 + lm) * 32 + lq * 8);
#pragma unroll
        for (int j = 0; j < 4; j++)
            bfr[j] = *(const bf16x8*)(Bs + (wn + j * 16 + lm) * 32 + lq * 8);
#pragma unroll
        for (int i = 0; i < 4; i++)
#pragma unroll
            for (int j = 0; j < 4; j++)
                acc[i][j] = MFMA16(af[i], bfr[j], acc[i][j]);
    }
#pragma unroll
    for (int j = 0; j < 4; j++) {
        int col = bn + wn + j * 16 + lm;
        float bv = sg.bias ? sg.bias[col] : 0.f;
#pragma unroll
        for (int i = 0; i < 4; i++) {
            int row0 = bm + wm + i * 16 + lq * 4;
#pragma unroll
            for (int rg = 0; rg < 4; rg++) {
                float v = acc[i][j][rg] + bv;
                if (sg.act == 2) v = 1.f / (1.f + __expf(-v));
                sg.Cf[(size_t)(row0 + rg) * N + col] = v;
            }
        }
    }
}

// ---------------- prep for k/v (per (t,kvh)); mega row stride 3072 ----------------
__global__ __launch_bounds__(128)
void prep_kv(float* __restrict__ mega, float* __restrict__ kkO,
             const float* __restrict__ kfirst, const float* __restrict__ vfirst,
             const float* __restrict__ kmix, const float* __restrict__ vmix,
             const float* __restrict__ cosT, const float* __restrict__ sinT,
             const float* __restrict__ knw) {
    __shared__ float sh[128];
    __shared__ float sh2[2];
    int b = blockIdx.x;
    int t = b >> 2, kvh = b & 3;
    int n = threadIdx.x;
    size_t kbase = (size_t)t * 3072 + 2048 + kvh * 128;
    size_t vbase = (size_t)t * 3072 + 2560 + kvh * 128;
    size_t fbase = (size_t)t * 512 + kvh * 128;
    float x = mega[kbase + n];
    float ssq = block_sum_128(x * x, sh2);
    float kn = knw[n] * (x * rsqrtf(ssq * (1.f / 128.f) + 1e-6f));
    sh[n] = kn;
    __syncthreads();
    float rot = (n < 64) ? -sh[n + 64] : sh[n - 64];
    float c = cosT[(size_t)t * 128 + n], s = sinT[(size_t)t * 128 + n];
    float kr = kn * c + rot * s;
    float kf = kr + (kfirst[fbase + n] - kr) * kmix[fbase + n];
    float s2 = block_sum_128(kf * kf, sh2);
    float kkv = kf / fmaxf(sqrtf(s2), 1e-12f);
    float vv = mega[vbase + n];
    float vf = vv + (vfirst[fbase + n] - vv) * vmix[fbase + n];
    mega[kbase + n] = kf;
    kkO[fbase + n] = kkv;
    mega[vbase + n] = vf;
}

// ---------------- prep for r / wdec / c (per (t,h)) ----------------
__global__ __launch_bounds__(128)
void prep_r(float* __restrict__ mega, float* __restrict__ Wl,
            const float* __restrict__ rk, float* __restrict__ cOut,
            const float* __restrict__ cosT, const float* __restrict__ sinT,
            const float* __restrict__ rnw) {
    __shared__ float sh[128];
    __shared__ float sh2[2];
    int b = blockIdx.x;
    int t = b >> 4, h = b & 15;
    int kv = h >> 2;
    int n = threadIdx.x;
    size_t rbase = (size_t)t * 3072 + h * 128;
    float x = mega[rbase + n];
    float ssq = block_sum_128(x * x, sh2);
    float rn = rnw[n] * (x * rsqrtf(ssq * (1.f / 128.f) + 1e-6f));
    sh[n] = rn;
    __syncthreads();
    float rot = (n < 64) ? -sh[n + 64] : sh[n - 64];
    float c = cosT[(size_t)t * 128 + n], s = sinT[(size_t)t * 128 + n];
    float rr = rn * c + rot * s;
    mega[rbase + n] = rr;
    size_t wb_ = (size_t)t * 2048 + h * 128 + n;
    float z = Wl[wb_];
    float nz = -z;
    float sp = fmaxf(nz, 0.f) + log1pf(expf(-fabsf(nz)));
    float w = -sp - 0.5f;
    Wl[wb_] = expf(-expf(w));
    float pc = rr * mega[(size_t)t * 3072 + 2048 + kv * 128 + n] * rk[h * 128 + n];
    float cs = block_sum_128(pc, sh2);
    if (n == 0) cOut[b] = cs;
}

// =====================================================================
// Chunked scan, L=32, 64 chunks (WY/UT transform).
// Frag-linear global layouts: ATt/Bnt/Knt/Vt stored so a wave's frag load
// is one contiguous 1KB read (lane*16B).  Element mapping for a [rows][k=32]
// operand: off = blk(row/16,k/32)*512 + ((k>>3)&3)*128 + (row&15)*8 + (k&7).
// Cloc stored lane-major per (iblock, ti): off = ii*512 + ti*256 + lane*4 + rg.
// =====================================================================

// ---- phase A: per (head, chunk) = 1024 blocks x 1 wave -------------
__global__ __launch_bounds__(64)
void scan_phaseA(const float* __restrict__ Wl, const float* __restrict__ megaF,
                 const float* __restrict__ aS, const float* __restrict__ kkB,
                 __bf16* __restrict__ ATt_g, __bf16* __restrict__ Rr_g,
                 __bf16* __restrict__ Bnt_g, __bf16* __restrict__ Knt_g,
                 __bf16* __restrict__ Vt_g, __bf16* __restrict__ Gbt_g,
                 __bf16* __restrict__ Gkt_g, float* __restrict__ Cloc_g,
                 float* __restrict__ cwL_g) {
    __shared__ __align__(16) __bf16 pool[27648];
    __bf16* Arm = pool;            // [32][136]
    __bf16* Brm = pool + 4352;     // [32][136]
    __bf16* Krm = pool + 8704;     // [32][136]
    __bf16* Rrm = pool + 13056;    // [32][136]
    __bf16* Vt  = pool + 17408;    // [128][40]
    __bf16* Mrm = pool + 22528;    // [32][40]
    __bf16* Mt  = pool + 23808;    // [32][40]
    __bf16* Prm = pool + 25088;    // [32][40]
    __bf16* Gtmp= pool + 26368;    // [32][40]
    __bf16* M2rm = pool + 4352;
    __bf16* M2t  = pool + 5632;
    __bf16* Xa   = pool + 6912;
    __bf16* Xb   = pool + 8192;
    __bf16* Tt   = pool + 9472;    // [t'][s] = T[s][t']   stride 40
    __bf16* PTt  = pool + 10752;   // [t'][s] = (P*T)[s][t']
    __bf16* Ant  = pool + 13056;   // [n][s] stride 32 (overlays Rrm after copy-out)

    const int l = threadIdx.x, lm = l & 15, lq = l >> 4;
    const int u = blockIdx.x, h = u >> 6, c = u & 63, kv = h >> 2;
    const int n0 = l, n1 = l + 64;

    float cw0 = 1.f, cw1 = 1.f;
    for (int t = 0; t < 32; ++t) {
        int tg = c * 32 + t;
        size_t hb = (size_t)tg * 2048 + h * 128;
        size_t mb = (size_t)tg * 3072;
        size_t kb = (size_t)tg * 512 + kv * 128;
        float wv0 = Wl[hb + n0], wv1 = Wl[hb + n1];
        float r0 = megaF[mb + h * 128 + n0], r1 = megaF[mb + h * 128 + n1];
        float q0 = kkB[kb + n0], q1 = kkB[kb + n1];
        float s0 = aS[hb + n0], s1 = aS[hb + n1];
        float k0 = megaF[mb + 2048 + kv * 128 + n0], k1 = megaF[mb + 2048 + kv * 128 + n1];
        float v0 = megaF[mb + 2560 + kv * 128 + n0], v1 = megaF[mb + 2560 + kv * 128 + n1];
        float cp0 = cw0, cp1 = cw1;
        cw0 *= wv0; cw1 *= wv1;
        float ic0 = 1.f / cw0, ic1 = 1.f / cw1;
        Arm[t * 136 + n0] = (__bf16)(-cp0 * q0);
        Arm[t * 136 + n1] = (__bf16)(-cp1 * q1);
        Brm[t * 136 + n0] = (__bf16)(q0 * s0 * ic0);
        Brm[t * 136 + n1] = (__bf16)(q1 * s1 * ic1);
        Krm[t * 136 + n0] = (__bf16)(k0 * ic0);
        Krm[t * 136 + n1] = (__bf16)(k1 * ic1);
        Rrm[t * 136 + n0] = (__bf16)(cw0 * r0);
        Rrm[t * 136 + n1] = (__bf16)(cw1 * r1);
        Vt[n0 * 40 + t] = (__bf16)v0;
        Vt[n1 * 40 + t] = (__bf16)v1;
    }
    cwL_g[(size_t)u * 128 + n0] = cw0;
    cwL_g[(size_t)u * 128 + n1] = cw1;

    auto mmLL = [&](const __bf16* Ao, const __bf16* Bo, bool incl, __bf16* dTr, __bf16* dDir) {
#pragma unroll
        for (int ri = 0; ri < 2; ri++)
#pragma unroll
        for (int ci = 0; ci < 2; ci++) {
            f32x4 acc = {};
#pragma unroll
            for (int s = 0; s < 4; s++) {
                bf16x8 af = *(const bf16x8*)(Ao + (ri * 16 + lm) * 136 + s * 32 + lq * 8);
                bf16x8 bf = *(const bf16x8*)(Bo + (ci * 16 + lm) * 136 + s * 32 + lq * 8);
                acc = MFMA16(af, bf, acc);
            }
#pragma unroll
            for (int rg = 0; rg < 4; rg++) {
                int rr = ri * 16 + lq * 4 + rg, cc = ci * 16 + lm;
                bool keep = incl ? (cc <= rr) : (cc < rr);
                __bf16 bv = (__bf16)(keep ? acc[rg] : 0.f);
                if (dTr)  dTr[cc * 40 + rr] = bv;
                if (dDir) dDir[rr * 40 + cc] = bv;
            }
        }
    };
    mmLL(Arm, Brm, false, Mrm, Mt);
    mmLL(Arm, Krm, false, Prm, nullptr);
    mmLL(Rrm, Brm, true, nullptr, Gtmp);
    for (int i = l; i < 512; i += 64) {
        int r = i >> 4, cp = i & 15;
        ((int*)(Gbt_g + (size_t)u * 1024))[i] = *(const int*)(Gtmp + r * 40 + cp * 2);
    }
    mmLL(Rrm, Krm, true, nullptr, Gtmp);
    for (int i = l; i < 512; i += 64) {
        int r = i >> 4, cp = i & 15;
        ((int*)(Gkt_g + (size_t)u * 1024))[i] = *(const int*)(Gtmp + r * 40 + cp * 2);
    }
    for (int i = l; i < 2048; i += 64) {
        int t = i >> 6, cp = i & 63;
        ((int*)(Rr_g + (size_t)u * 4096))[i] = *(const int*)(Rrm + t * 136 + cp * 2);
    }
    // B^/K^/V out in frag-linear layout: u32 idx = blk(n>>4)*256 + (tp>>2)*64 + (n&15)*4 + (tp&3)
    for (int i = l; i < 2048; i += 64) {
        int n = i >> 4, tp = i & 15;
        int idx = (n >> 4) * 256 + (tp >> 2) * 64 + (n & 15) * 4 + (tp & 3);
        unsigned int lo = ((const unsigned short*)Brm)[(2 * tp) * 136 + n];
        unsigned int hi = ((const unsigned short*)Brm)[(2 * tp + 1) * 136 + n];
        ((unsigned int*)(Bnt_g + (size_t)u * 4096))[idx] = lo | (hi << 16);
        unsigned int lo2 = ((const unsigned short*)Krm)[(2 * tp) * 136 + n];
        unsigned int hi2 = ((const unsigned short*)Krm)[(2 * tp + 1) * 136 + n];
        ((unsigned int*)(Knt_g + (size_t)u * 4096))[idx] = lo2 | (hi2 << 16);
        ((unsigned int*)(Vt_g + (size_t)u * 4096))[idx] = *(const unsigned int*)(Vt + n * 40 + tp * 2);
    }

    // Xa = I + M ; Ant = A~^T (into Rrm region — reads above precede in order)
    for (int i = l; i < 1024; i += 64) {
        int s = i >> 5, t = i & 31;
        Xa[s * 40 + t] = (s == t) ? (__bf16)1.f : Mrm[s * 40 + t];
    }
    for (int i = l; i < 4096; i += 64) {
        int s = i & 31, n = i >> 5;
        Ant[n * 32 + s] = Arm[s * 136 + n];
    }

    auto mat32 = [&](const __bf16* Ao, const __bf16* Bo, const __bf16* accIn,
                     __bf16* oRm, __bf16* oT) {
#pragma unroll
        for (int ri = 0; ri < 2; ri++)
#pragma unroll
        for (int ci = 0; ci < 2; ci++) {
            f32x4 acc = {};
            if (accIn) {
#pragma unroll
                for (int rg = 0; rg < 4; rg++)
                    acc[rg] = (float)accIn[(ri * 16 + lq * 4 + rg) * 40 + ci * 16 + lm];
            }
            bf16x8 af = *(const bf16x8*)(Ao + (ri * 16 + lm) * 40 + lq * 8);
            bf16x8 bf = *(const bf16x8*)(Bo + (ci * 16 + lm) * 40 + lq * 8);
            acc = MFMA16(af, bf, acc);
#pragma unroll
            for (int rg = 0; rg < 4; rg++) {
                int rr = ri * 16 + lq * 4 + rg, cc = ci * 16 + lm;
                __bf16 bv = (__bf16)acc[rg];
                if (oRm) oRm[rr * 40 + cc] = bv;
                if (oT)  oT[cc * 40 + rr] = bv;
            }
        }
    };
    mat32(Mrm, Mt, nullptr, M2rm, M2t);
    mat32(Xa, M2t, Xa, Xb, nullptr);
    mat32(M2rm, M2t, nullptr, Mrm, Mt);
    mat32(Xb, Mt, Xb, Xa, nullptr);
    mat32(Mrm, Mt, nullptr, M2rm, M2t);
    mat32(Xa, M2t, Xa, Xb, nullptr);
    mat32(M2rm, M2t, nullptr, Mrm, Mt);
    mat32(Xb, Mt, Xb, nullptr, Tt);
    mat32(Tt, Prm, nullptr, PTt, nullptr);

    // ATt[t'][n] via MFMA, written in frag-linear layout
#pragma unroll
    for (int ti = 0; ti < 2; ti++) {
        bf16x8 af = *(const bf16x8*)(Tt + (ti * 16 + lm) * 40 + lq * 8);
#pragma unroll
        for (int ni = 0; ni < 8; ni++) {
            f32x4 accv = {};
            bf16x8 bfv = *(const bf16x8*)(Ant + (ni * 16 + lm) * 32 + lq * 8);
            accv = MFMA16(af, bfv, accv);
#pragma unroll
            for (int rg = 0; rg < 4; rg++) {
                // element (row t' = ti*16+lq*4+rg, col n = ni*16+lm)
                int off = (ti * 4 + (ni >> 1)) * 512 + ((ni & 1) * 2 + (lm >> 3)) * 128
                        + (lq * 4 + rg) * 8 + (lm & 7);
                ATt_g[(size_t)u * 4096 + off] = (__bf16)accv[rg];
            }
        }
    }
    // C_loc = V * (P T), stored lane-major per (ii, ti): vectorized f32x4 stores
#pragma unroll
    for (int ii = 0; ii < 8; ii++)
#pragma unroll
    for (int ti = 0; ti < 2; ti++) {
        f32x4 acc = {};
        bf16x8 af = *(const bf16x8*)(Vt + (ii * 16 + lm) * 40 + lq * 8);
        bf16x8 bf = *(const bf16x8*)(PTt + (ti * 16 + lm) * 40 + lq * 8);
        acc = MFMA16(af, bf, acc);
        *(f32x4*)(Cloc_g + (size_t)u * 4096 + ii * 512 + ti * 256 + l * 4) = acc;
    }
}

// ---- phase B: 1 wave/block, barrier-free, DEPTH-3 register prefetch ----
struct Ops {
    bf16x8 at[8], bn[8], kn[8], vf;
    f32x4 cl[2];
    float cw[8];
};

__global__ __launch_bounds__(64, 1)
void scan_phaseB(const __bf16* __restrict__ ATt_g, const __bf16* __restrict__ Bnt_g,
                 const __bf16* __restrict__ Knt_g, const __bf16* __restrict__ Vt_g,
                 const float* __restrict__ Cloc_g, const float* __restrict__ cwL_g,
                 __bf16* __restrict__ Sg, __bf16* __restrict__ Cg) {
    __shared__ __align__(16) __bf16 Sbf[16 * 136];
    __shared__ __align__(16) __bf16 Cbf[16 * 40];
    const int h = blockIdx.y, i0 = blockIdx.x * 16;
    const int l = threadIdx.x, lm = l & 15, lq = l >> 4;
    f32x4 st[8];
#pragma unroll
    for (int cc = 0; cc < 8; cc++) st[cc] = (f32x4){0.f, 0.f, 0.f, 0.f};

    auto loadOps = [&](int c, Ops& o) {
        size_t u = (size_t)h * 64 + c;
        const __bf16* ab = ATt_g + u * 4096 + (size_t)l * 8;
        const __bf16* bb = Bnt_g + u * 4096 + (size_t)l * 8;
        const __bf16* kb = Knt_g + u * 4096 + (size_t)l * 8;
#pragma unroll
        for (int j = 0; j < 8; j++) {
            o.at[j] = *(const bf16x8*)(ab + j * 512);
            o.bn[j] = *(const bf16x8*)(bb + j * 512);
            o.kn[j] = *(const bf16x8*)(kb + j * 512);
        }
        o.vf = *(const bf16x8*)(Vt_g + u * 4096 + (i0 >> 4) * 512 + (size_t)l * 8);
        const float* clb = Cloc_g + u * 4096 + (i0 >> 4) * 512 + (size_t)l * 4;
        o.cl[0] = *(const f32x4*)(clb);
        o.cl[1] = *(const f32x4*)(clb + 256);
#pragma unroll
        for (int cc = 0; cc < 8; cc++) o.cw[cc] = cwL_g[u * 128 + cc * 16 + lm];
    };

    auto computeChunk = [&](int c, const Ops& o) {
        size_t u = (size_t)h * 64 + c;
        // state (f32 C-layout) -> bf16 LDS [i][n]; wave-local, in-order DS
#pragma unroll
        for (int cc = 0; cc < 8; cc++)
#pragma unroll
            for (int rg = 0; rg < 4; rg++)
                Sbf[(lq * 4 + rg) * 136 + cc * 16 + lm] = (__bf16)st[cc][rg];
        bf16x8 saf[4];
#pragma unroll
        for (int s = 0; s < 4; s++)
            saf[s] = *(const bf16x8*)(Sbf + lm * 136 + s * 32 + lq * 8);
        f32x4 cacc[2];
#pragma unroll
        for (int ti = 0; ti < 2; ti++) {
            f32x4 acc = o.cl[ti];
#pragma unroll
            for (int s = 0; s < 4; s++) acc = MFMA16(saf[s], o.at[ti * 4 + s], acc);
            cacc[ti] = acc;
        }
#pragma unroll
        for (int ti = 0; ti < 2; ti++)
#pragma unroll
            for (int rg = 0; rg < 4; rg++)
                Cbf[(lq * 4 + rg) * 40 + ti * 16 + lm] = (__bf16)cacc[ti][rg];
        bf16x8 cf = *(const bf16x8*)(Cbf + lm * 40 + lq * 8);
        // dump S0 (frag layout) and C for phaseC — off the dependency chain
#pragma unroll
        for (int s = 0; s < 4; s++)
            *(bf16x8*)(Sg + u * 16384 + (size_t)(i0 + lm) * 128 + s * 32 + lq * 8) = saf[s];
        *(bf16x8*)(Cg + u * 4096 + (size_t)(i0 + lm) * 32 + lq * 8) = cf;
        // S = (S0 + C*B^T + V*K^T) * cwL
#pragma unroll
        for (int cc = 0; cc < 8; cc++) {
            st[cc] = MFMA16(cf, o.bn[cc], st[cc]);
            st[cc] = MFMA16(o.vf, o.kn[cc], st[cc]);
#pragma unroll
            for (int rg = 0; rg < 4; rg++) st[cc][rg] *= o.cw[cc];
        }
    };

    Ops A, B, C;
    loadOps(0, A);
    loadOps(1, B);
    loadOps(2, C);
    int c = 0;
    for (; c + 2 < 64; c += 3) {
        computeChunk(c, A);
        if (c + 3 < 64) loadOps(c + 3, A);
        computeChunk(c + 1, B);
        if (c + 4 < 64) loadOps(c + 4, B);
        computeChunk(c + 2, C);
        if (c + 5 < 64) loadOps(c + 5, C);
    }
    computeChunk(63, A);
}

// ---- phase C: Y = S0*R^ + C*Gb + V*Gk, fused output gating (1 wave, no barrier) ----
__global__ __launch_bounds__(64)
void scan_phaseC(const __bf16* __restrict__ Sg, const __bf16* __restrict__ Cg,
                 const __bf16* __restrict__ Rr_g, const __bf16* __restrict__ Vt_g,
                 const __bf16* __restrict__ Gbt_g, const __bf16* __restrict__ Gkt_g,
                 const float* __restrict__ cB, const float* __restrict__ megaF,
                 const float* __restrict__ gB, __bf16* __restrict__ out) {
    __shared__ float Ybuf[32 * 18];
    const int bx = blockIdx.x, h = blockIdx.y;
    const int c = bx >> 3, i0 = (bx & 7) * 16;
    const int l = threadIdx.x, lm = l & 15, lq = l >> 4;
    const size_t u = (size_t)h * 64 + c;
    bf16x8 saf[4];
#pragma unroll
    for (int s = 0; s < 4; s++)
        saf[s] = *(const bf16x8*)(Sg + u * 16384 + (size_t)(i0 + lm) * 128 + s * 32 + lq * 8);
    bf16x8 cf = *(const bf16x8*)(Cg + u * 4096 + (size_t)(i0 + lm) * 32 + lq * 8);
    bf16x8 vf = *(const bf16x8*)(Vt_g + u * 4096 + (i0 >> 4) * 512 + (size_t)l * 8);
#pragma unroll
    for (int ti = 0; ti < 2; ti++) {
        f32x4 acc = {};
#pragma unroll
        for (int s = 0; s < 4; s++) {
            bf16x8 rp = *(const bf16x8*)(Rr_g + u * 4096 + (ti * 16 + lm) * 128 + s * 32 + lq * 8);
            acc = MFMA16(saf[s], rp, acc);
        }
        bf16x8 gb = *(const bf16x8*)(Gbt_g + u * 1024 + (ti * 16 + lm) * 32 + lq * 8);
        acc = MFMA16(cf, gb, acc);
        bf16x8 gk = *(const bf16x8*)(Gkt_g + u * 1024 + (ti * 16 + lm) * 32 + lq * 8);
        acc = MFMA16(vf, gk, acc);
#pragma unroll
        for (int rg = 0; rg < 4; rg++)
            Ybuf[(ti * 16 + lm) * 18 + lq * 4 + rg] = acc[rg];
    }
    const int kv = h >> 2;
#pragma unroll
    for (int pass = 0; pass < 8; pass++) {
        int t = pass * 4 + lq;
        int tg = c * 32 + t;
        int col = h * 128 + i0 + lm;
        float yv = Ybuf[t * 18 + lm];
        float cv = cB[tg * 16 + h];
        float vv = megaF[(size_t)tg * 3072 + 2560 + kv * 128 + i0 + lm];
        float gg = gB[(size_t)tg * 2048 + col];
        out[(size_t)tg * 2048 + col] = (__bf16)((yv + cv * vv) * gg);
    }
}

// ---------------- orchestration ----------------
extern "C" void kernel_launch(void* const* d_in, const int* in_sizes, int n_in,
                              void* d_out, int out_size, void* d_ws, size_t ws_size,
                              hipStream_t stream) {
    (void)in_sizes; (void)n_in; (void)out_size; (void)ws_size;
    const float* x      = (const float*)d_in[0];
    const float* vfirst = (const float*)d_in[1];
    const float* kfirst = (const float*)d_in[2];
    const float* amask  = (const float*)d_in[3];
    const float* cosT   = (const float*)d_in[4];
    const float* sinT   = (const float*)d_in[5];
    const float* w0     = (const float*)d_in[6];
    const float* w1     = (const float*)d_in[7];
    const float* w2     = (const float*)d_in[8];
    const float* a0     = (const float*)d_in[9];
    const float* a1     = (const float*)d_in[10];
    const float* a2     = (const float*)d_in[11];
    const float* v0     = (const float*)d_in[12];
    const float* v1     = (const float*)d_in[13];
    const float* v2     = (const float*)d_in[14];
    const float* k0     = (const float*)d_in[15];
    const float* k1     = (const float*)d_in[16];
    const float* k2     = (const float*)d_in[17];
    const float* g1     = (const float*)d_in[18];
    const float* g2     = (const float*)d_in[19];
    const float* rk     = (const float*)d_in[20];
    const float* rnw    = (const float*)d_in[21];
    const float* knw    = (const float*)d_in[22];
    const float* W_r    = (const float*)d_in[23];
    const float* W_k    = (const float*)d_in[24];
    const float* W_v    = (const float*)d_in[25];
    const float* W_o    = (const float*)d_in[26];

    char* p = (char*)d_ws;
    auto take = [&](size_t bytes) { char* r = p; p += (bytes + 255) & ~(size_t)255; return r; };
    __bf16* arena   = (__bf16*)take((size_t)3616 * 2048 * 2);
    __bf16* xmb     = (__bf16*)take((size_t)T_ * C_ * 2);
    float*  megaF   = (float*)take((size_t)T_ * 3072 * 4);
    __bf16* megaB   = (__bf16*)take((size_t)T_ * 544 * 2);
    __bf16* w2T     = (__bf16*)take((size_t)2048 * 160 * 2);
    __bf16* a2T     = (__bf16*)take((size_t)2048 * 96 * 2);
    __bf16* v2T     = (__bf16*)take((size_t)512 * 64 * 2);
    __bf16* k2T     = (__bf16*)take((size_t)512 * 64 * 2);
    __bf16* g2T     = (__bf16*)take((size_t)2048 * 160 * 2);
    float*  Wl      = (float*)take((size_t)T_ * 2048 * 4);   // wdec; reused as Sg
    float*  aS      = (float*)take((size_t)T_ * 2048 * 4);   // a; tail of Sg
    float*  gB      = (float*)take((size_t)T_ * 2048 * 4);
    float*  kkB     = (float*)take((size_t)T_ * 512 * 4);    // kk; reused as Cg
    float*  vmx     = (float*)take((size_t)T_ * 512 * 4);    // tail of Cg
    float*  kmx     = (float*)take((size_t)T_ * 512 * 4);
    float*  cB      = (float*)take((size_t)T_ * H_ * 4);
    __bf16* ATt_g   = (__bf16*)take((size_t)1024 * 4096 * 2);
    __bf16* Rr_g    = (__bf16*)take((size_t)1024 * 4096 * 2);
    __bf16* Bnt_g   = (__bf16*)take((size_t)1024 * 4096 * 2);
    __bf16* Knt_g   = (__bf16*)take((size_t)1024 * 4096 * 2);
    __bf16* Vt_g    = (__bf16*)take((size_t)1024 * 4096 * 2);
    __bf16* Gbt_g   = (__bf16*)take((size_t)1024 * 1024 * 2);
    __bf16* Gkt_g   = (__bf16*)take((size_t)1024 * 1024 * 2);
    float*  Cloc_g  = (float*)take((size_t)1024 * 4096 * 4);
    float*  cwL_g   = (float*)take((size_t)1024 * 128 * 4);
    __bf16* Sg = (__bf16*)Wl;
    __bf16* Cg = (__bf16*)kkB;

    xm_to_bf16<<<(T_ * C_ / 4) / 256, 256, 0, stream>>>(x, amask, xmb);

    TrBatch tb;
    {
        const float* srcs[13] = {W_r, W_k, W_v, w1, a1, v1, k1, g1, w2, a2, v2, k2, g2};
        __bf16* dsts[13] = {arena, arena + (size_t)2048 * 2048, arena + (size_t)2560 * 2048,
                            arena + (size_t)3072 * 2048, arena + (size_t)3232 * 2048,
                            arena + (size_t)3328 * 2048, arena + (size_t)3392 * 2048,
                            arena + (size_t)3456 * 2048, w2T, a2T, v2T, k2T, g2T};
        int Rs[13] = {2048, 2048, 2048, 2048, 2048, 2048, 2048, 2048, 160, 96, 64, 64, 160};
        int Cs[13] = {2048, 512, 512, 160, 96, 64, 64, 160, 2048, 2048, 512, 512, 2048};
        int cum = 0;
        for (int e = 0; e < 13; e++) {
            tb.d[e].src = srcs[e]; tb.d[e].dst = dsts[e];
            tb.d[e].R = Rs[e]; tb.d[e].C = Cs[e]; tb.d[e].tileStart = cum;
            cum += ((Rs[e] + 31) / 32) * ((Cs[e] + 31) / 32);
        }
        tb.n = 13;
        transpose_batch<<<cum, 256, 0, stream>>>(tb);
    }

    gemm_bf16<2><<<dim3(29, 16), 256, 0, stream>>>(xmb, 2048, arena, nullptr, megaF, megaB, 3616, 2048, 0);

    GB5 gb;
    gb.s[0] = {w2T, w0, Wl,  0,   160, 2048, 0, 0};
    gb.s[1] = {a2T, a0, aS,  160, 96,  2048, 2, 16};
    gb.s[2] = {v2T, v0, vmx, 256, 64,  512,  2, 32};
    gb.s[3] = {k2T, k0, kmx, 320, 64,  512,  2, 36};
    gb.s[4] = {g2T, nullptr, gB, 384, 160, 2048, 0, 40};
    gemm_group<<<dim3(56, 16), 256, 0, stream>>>(megaB, gb);

    prep_kv<<<T_ * KVH_, 128, 0, stream>>>(megaF, kkB, kfirst, vfirst, kmx, vmx, cosT, sinT, knw);
    prep_r<<<T_ * H_, 128, 0, stream>>>(megaF, Wl, rk, cB, cosT, sinT, rnw);

    scan_phaseA<<<1024, 64, 0, stream>>>(Wl, megaF, aS, kkB, ATt_g, Rr_g, Bnt_g, Knt_g,
                                         Vt_g, Gbt_g, Gkt_g, Cloc_g, cwL_g);
    scan_phaseB<<<dim3(8, 16), 64, 0, stream>>>(ATt_g, Bnt_g, Knt_g, Vt_g, Cloc_g, cwL_g, Sg, Cg);
    scan_phaseC<<<dim3(512, 16), 64, 0, stream>>>(Sg, Cg, Rr_g, Vt_g, Gbt_g, Gkt_g,
                                                  cB, megaF, gB, xmb);

    transpose_f32_bf16<<<dim3(64, 64), 256, 0, stream>>>(W_o, arena, 2048, 2048);
    gemm_bf16<0><<<dim3(16, 16), 256, 0, stream>>>(xmb, 2048, arena, nullptr, (float*)d_out, nullptr, 2048, 2048, 0);
}